// Round 17
// baseline (7960.503 us; speedup 1.0000x reference)
//
#include <hip/hip_runtime.h>
#include <hip/hip_fp16.h>

typedef unsigned short u16;
typedef unsigned int u32;
typedef unsigned long long u64;

#define E 2048
#define T_STEPS 512

// ---------------- helpers ----------------
// dequant 8 int4 (offset-8 nibbles) from one u32 against 8 h-values
__device__ __forceinline__ float dot8i4(u32 v, float4 a, float4 b, float acc) {
    acc = fmaf((float)((int)(v & 15u) - 8), a.x, acc);
    acc = fmaf((float)((int)((v >> 4) & 15u) - 8), a.y, acc);
    acc = fmaf((float)((int)((v >> 8) & 15u) - 8), a.z, acc);
    acc = fmaf((float)((int)((v >> 12) & 15u) - 8), a.w, acc);
    acc = fmaf((float)((int)((v >> 16) & 15u) - 8), b.x, acc);
    acc = fmaf((float)((int)((v >> 20) & 15u) - 8), b.y, acc);
    acc = fmaf((float)((int)((v >> 24) & 15u) - 8), b.z, acc);
    acc = fmaf((float)((int)(v >> 28) - 8), b.w, acc);
    return acc;
}
// dequant 32 int3 (offset-4) packed in 96-bit (A,B,C) against 32 h-values
__device__ __forceinline__ float dot32i3(u32 A, u32 B, u32 C,
                                         const float4* __restrict__ h, float acc) {
    const u64 AB = ((u64)B << 32) | A;
    const u64 BC = ((u64)C << 32) | B;
    const float* hf = (const float*)h;
#pragma unroll
    for (int i = 0; i < 32; ++i) {
        u32 v;
        if (i <= 20) v = (u32)(AB >> (3 * i)) & 7u;          // compile-time shifts
        else         v = (u32)(BC >> (3 * i - 32)) & 7u;
        acc = fmaf((float)((int)v - 4), hf[i], acc);
    }
    return acc;
}
__device__ __forceinline__ float wred(float t) {
#pragma unroll
    for (int off = 32; off > 0; off >>= 1) t += __shfl_xor(t, off);
    return t;
}
__device__ __forceinline__ float sigm(float v) { return 1.f / (1.f + expf(-v)); }

// load 4 fp16 elems at h16 + idx (8B) -> float4 (works for global or LDS)
__device__ __forceinline__ float4 ld4h(const __half* h16, int idx) {
    uint2 u = *(const uint2*)(h16 + idx);
    __half2 p0 = *reinterpret_cast<const __half2*>(&u.x);
    __half2 p1 = *reinterpret_cast<const __half2*>(&u.y);
    float2 f0 = __half22float2(p0);
    float2 f1 = __half22float2(p1);
    return make_float4(f0.x, f0.y, f1.x, f1.y);
}

// ---------------- prep kernels ----------------

// W_comb[r][c] = sum_k W_ih0[r][k] * W_out[k][c]  (fp32; 8192 x 2048)
__global__ __launch_bounds__(256) void k_wcomb(const float* __restrict__ wih0,
                                               const float* __restrict__ wout,
                                               float* __restrict__ wc) {
    __shared__ float a[8 * 128];
    int r0 = blockIdx.y * 8;
    int c = blockIdx.x * 256 + threadIdx.x;
    for (int i = threadIdx.x; i < 8 * 128; i += 256) a[i] = wih0[r0 * 128 + i];
    __syncthreads();
    float acc[8] = {0.f, 0.f, 0.f, 0.f, 0.f, 0.f, 0.f, 0.f};
    for (int k = 0; k < 128; ++k) {
        float b = wout[k * E + c];
#pragma unroll
        for (int j = 0; j < 8; ++j) acc[j] = fmaf(a[j * 128 + k], b, acc[j]);
    }
#pragma unroll
    for (int j = 0; j < 8; ++j) wc[(size_t)(r0 + j) * E + c] = acc[j];
}

// int4 quantization, elem-packed: input row r (q=r>>11, e=r&2047) -> packed row
// p = e*4+q (256 u32); lane l covers elems {j*256+l*4..+3}; u32 k holds groups 2k,2k+1
__global__ __launch_bounds__(64) void k_quant4p(const float* __restrict__ in,
                                                u32* __restrict__ P,
                                                float* __restrict__ sP) {
    const int r = blockIdx.x;
    const int l = threadIdx.x;
    const int q = r >> 11, e = r & 2047;
    const int p = e * 4 + q;
    const float* row = in + (size_t)r * E;
    float4 v[8];
    float mx = 0.f;
#pragma unroll
    for (int j = 0; j < 8; ++j) {
        v[j] = *(const float4*)(row + j * 256 + l * 4);
        mx = fmaxf(mx, fmaxf(fmaxf(fabsf(v[j].x), fabsf(v[j].y)),
                             fmaxf(fabsf(v[j].z), fabsf(v[j].w))));
    }
#pragma unroll
    for (int off = 32; off > 0; off >>= 1) mx = fmaxf(mx, __shfl_xor(mx, off));
    mx = fmaxf(mx, 1e-30f);
    const float inv = 7.f / mx;
    const float* vf = (const float*)v;
    u32 pk[4];
#pragma unroll
    for (int k = 0; k < 4; ++k) {
        u32 acc = 0u;
#pragma unroll
        for (int i = 0; i < 8; ++i) {
            const int j = 2 * k + (i >> 2);
            float x = vf[j * 4 + (i & 3)];
            int qv = (int)rintf(x * inv);
            qv = qv < -7 ? -7 : (qv > 7 ? 7 : qv);
            acc |= ((u32)(qv + 8)) << (4 * i);
        }
        pk[k] = acc;
    }
    ((uint4*)(P + (size_t)p * 256))[l] = make_uint4(pk[0], pk[1], pk[2], pk[3]);
    if (l == 0) sP[p] = mx / 7.f;
}

// int3 quantization, packed row p = e*4+q occupies 192 u32:
// lane l: planes A,B interleaved as uint2 at [p*192 + 2l], plane C at [p*192+128+l]
__global__ __launch_bounds__(64) void k_quant3p(const float* __restrict__ in,
                                                u32* __restrict__ P,
                                                float* __restrict__ sP) {
    const int r = blockIdx.x;
    const int l = threadIdx.x;
    const int q = r >> 11, e = r & 2047;
    const int p = e * 4 + q;
    const float* row = in + (size_t)r * E;
    float4 v[8];
    float mx = 0.f;
#pragma unroll
    for (int j = 0; j < 8; ++j) {
        v[j] = *(const float4*)(row + j * 256 + l * 4);
        mx = fmaxf(mx, fmaxf(fmaxf(fabsf(v[j].x), fabsf(v[j].y)),
                             fmaxf(fabsf(v[j].z), fabsf(v[j].w))));
    }
#pragma unroll
    for (int off = 32; off > 0; off >>= 1) mx = fmaxf(mx, __shfl_xor(mx, off));
    mx = fmaxf(mx, 1e-30f);
    const float inv = 3.f / mx;
    const float* vf = (const float*)v;
    u32 w3[3] = {0u, 0u, 0u};
#pragma unroll
    for (int i = 0; i < 32; ++i) {
        float x = vf[i];
        int qv = (int)rintf(x * inv);
        qv = qv < -3 ? -3 : (qv > 3 ? 3 : qv);
        const u32 u = (u32)(qv + 4);
        const int bit = 3 * i, word = bit >> 5, off = bit & 31;
        w3[word] |= u << off;
        if (off > 29 && word < 2) w3[word + 1] |= u >> (32 - off);
    }
    u32* dst = P + (size_t)p * 192;
    dst[2 * l] = w3[0];
    dst[2 * l + 1] = w3[1];
    dst[128 + l] = w3[2];
    if (l == 0) sP[p] = mx / 3.f;
}

// W_outT[e][d] = W_out[d][e]
__global__ void k_transpose_wout(const float* __restrict__ wout, float* __restrict__ woutT) {
    int o = blockIdx.x * blockDim.x + threadIdx.x;
    if (o >= E * 128) return;
    int e = o >> 7, d = o & 127;
    woutT[o] = wout[d * E + e];
}

// bcomb[r] = b_ih0[r]+b_hh0[r]+dot(W_ih0[r],b_out);  bias1[r] = b_ih1[r]+b_hh1[r]
__global__ void k_bcomb(const float* __restrict__ wih0, const float* __restrict__ bout,
                        const float* __restrict__ bih0, const float* __restrict__ bhh0,
                        const float* __restrict__ bih1, const float* __restrict__ bhh1,
                        float* __restrict__ bcomb, float* __restrict__ bias1) {
    int r = blockIdx.x * blockDim.x + threadIdx.x;
    if (r >= 4 * E) return;
    float acc = bih0[r] + bhh0[r];
    const float* w = wih0 + (size_t)r * 128;
#pragma unroll 8
    for (int k = 0; k < 128; ++k) acc = fmaf(w[k], bout[k], acc);
    bcomb[r] = acc;
    bias1[r] = bih1[r] + bhh1[r];
}

// hist[0] = lat (fp16), h0buf slot0 = lat (fp16), c0 = c1 = 0
__global__ void k_init(const float* __restrict__ lat, __half* __restrict__ hist0,
                       __half* __restrict__ h0buf0, float* __restrict__ c0,
                       float* __restrict__ c1) {
    int i = blockIdx.x * blockDim.x + threadIdx.x;
    if (i >= E) return;
    __half v = __float2half(lat[i]);
    hist0[i] = v;
    h0buf0[i] = v;
    c0[i] = 0.f;
    c1[i] = 0.f;
}

// ---------------- step kernel: one LSTM layer, 8 elems/block, 8 indep waves ----------
// wave w owns elem e = 8b + w. A-matrix int4 (PA + e*1024 u32) dots inA;
// B-matrix int3 (PB + e*768 u32) dots inB. Acts staged through LDS once per block.
__global__ __launch_bounds__(512) void k_stepq(
    const u32* __restrict__ PA, const float* __restrict__ sA,
    const u32* __restrict__ PB, const float* __restrict__ sB,
    const __half* __restrict__ inA, const __half* __restrict__ inB,
    const float* __restrict__ bias, float* __restrict__ c,
    __half* __restrict__ hout) {
    const int tid = threadIdx.x;
    const int e = blockIdx.x * 8 + (tid >> 6);
    const int l = tid & 63;

    // weight loads first (independent of predecessor kernel)
    const u32* wp4 = PA + (size_t)e * 1024;
    const u32* wp3 = PB + (size_t)e * 768;
    uint4 w4[4];
    uint2 ab3[4];
    u32 c3[4];
#pragma unroll
    for (int q = 0; q < 4; ++q) {
        w4[q] = ((const uint4*)(wp4 + q * 256))[l];
        ab3[q] = ((const uint2*)(wp3 + q * 192))[l];
        c3[q] = wp3[q * 192 + 128 + l];
    }

    // stage both act vectors (4KB each) through LDS, one coalesced pass
    __shared__ uint4 sh[512];
    if (tid < 256) sh[tid] = ((const uint4*)inA)[tid];
    else           sh[tid] = ((const uint4*)inB)[tid - 256];
    __syncthreads();
    const __half* hAp = (const __half*)sh;
    const __half* hBp = (const __half*)(sh + 256);

    float4 hA[8], hB[8];
#pragma unroll
    for (int j = 0; j < 8; ++j) {
        hA[j] = ld4h(hAp, j * 256 + l * 4);
        hB[j] = ld4h(hBp, j * 256 + l * 4);
    }

    const float* sAe = sA + e * 4;
    const float* sBe = sB + e * 4;
    float g[4];
#pragma unroll
    for (int q = 0; q < 4; ++q) {
        float accA = 0.f;
        accA = dot8i4(w4[q].x, hA[0], hA[1], accA);
        accA = dot8i4(w4[q].y, hA[2], hA[3], accA);
        accA = dot8i4(w4[q].z, hA[4], hA[5], accA);
        accA = dot8i4(w4[q].w, hA[6], hA[7], accA);
        float accB = dot32i3(ab3[q].x, ab3[q].y, c3[q], hB, 0.f);
        g[q] = wred(accA * sAe[q] + accB * sBe[q]);
    }

    if (l == 0) {
        float gi = g[0] + bias[e];
        float gf = g[1] + bias[E + e];
        float gg = g[2] + bias[2 * E + e];
        float go = g[3] + bias[3 * E + e];
        float cn = fmaf(sigm(gf), c[e], sigm(gi) * tanhf(gg));
        c[e] = cn;
        hout[e] = __float2half(sigm(go) * tanhf(cn));
    }
}

// ---------------- final output GEMM: out[t] = Wout @ hist[t] + bout ----------------
__global__ __launch_bounds__(128) void k_out(const float* __restrict__ woutT,
                                             const __half* __restrict__ hist,
                                             const float* __restrict__ bout,
                                             float* __restrict__ out) {
    __shared__ float h[E];
    int t = blockIdx.x, d = threadIdx.x;
    for (int i = d; i < E; i += 128) h[i] = __half2float(hist[(size_t)t * E + i]);
    __syncthreads();
    float acc0 = bout[d], acc1 = 0.f;
#pragma unroll 4
    for (int k = 0; k < E; k += 2) {
        acc0 = fmaf(woutT[k * 128 + d], h[k], acc0);
        acc1 = fmaf(woutT[(k + 1) * 128 + d], h[k + 1], acc1);
    }
    out[t * 128 + d] = acc0 + acc1;
}

extern "C" void kernel_launch(void* const* d_in, const int* in_sizes, int n_in,
                              void* d_out, int out_size, void* d_ws, size_t ws_size,
                              hipStream_t stream) {
    const float* lat = (const float*)d_in[0];
    const float* wih0 = (const float*)d_in[1];
    const float* whh0 = (const float*)d_in[2];
    const float* bih0 = (const float*)d_in[3];
    const float* bhh0 = (const float*)d_in[4];
    const float* wih1 = (const float*)d_in[5];
    const float* whh1 = (const float*)d_in[6];
    const float* bih1 = (const float*)d_in[7];
    const float* bhh1 = (const float*)d_in[8];
    const float* wout = (const float*)d_in[9];
    const float* bout = (const float*)d_in[10];

    const size_t P4B = (size_t)E * 4096;  // int4: 8.39 MB
    const size_t P3B = (size_t)E * 3072;  // int3: 6.29 MB
    char* p = (char*)d_ws;
    u32* PA0 = (u32*)p; p += P4B;  // layer0 cross: Qcomb (x h1)
    u32* PB0 = (u32*)p; p += P3B;  // layer0 recur: Qhh0 (x h0)
    u32* PA1 = (u32*)p; p += P4B;  // layer1 cross: Qih1 (x h0)
    u32* PB1 = (u32*)p; p += P3B;  // layer1 recur: Qhh1 (x h1)
    float* sA0 = (float*)p; p += (size_t)4 * E * 4;
    float* sB0 = (float*)p; p += (size_t)4 * E * 4;
    float* sA1 = (float*)p; p += (size_t)4 * E * 4;
    float* sB1 = (float*)p; p += (size_t)4 * E * 4;
    float* WcF = (float*)p; p += (size_t)4 * E * E * 4;  // 67 MB temp
    float* woutT = (float*)p; p += (size_t)E * 128 * 4;
    float* bcomb = (float*)p; p += (size_t)4 * E * 4;
    float* bias1 = (float*)p; p += (size_t)4 * E * 4;
    __half* hist = (__half*)p;  p += (size_t)T_STEPS * E * 2;
    __half* h0buf = (__half*)p; p += (size_t)2 * E * 2;
    float* c0 = (float*)p;    p += (size_t)E * 4;
    float* c1 = (float*)p;    p += (size_t)E * 4;

    k_wcomb<<<dim3(8, 1024), 256, 0, stream>>>(wih0, wout, WcF);
    k_quant4p<<<4 * E, 64, 0, stream>>>(WcF, PA0, sA0);
    k_quant3p<<<4 * E, 64, 0, stream>>>(whh0, PB0, sB0);
    k_quant4p<<<4 * E, 64, 0, stream>>>(wih1, PA1, sA1);
    k_quant3p<<<4 * E, 64, 0, stream>>>(whh1, PB1, sB1);
    k_transpose_wout<<<(E * 128 + 255) / 256, 256, 0, stream>>>(wout, woutT);
    k_bcomb<<<(4 * E + 255) / 256, 256, 0, stream>>>(wih0, bout, bih0, bhh0, bih1, bhh1,
                                                     bcomb, bias1);
    k_init<<<(E + 255) / 256, 256, 0, stream>>>(lat, hist, h0buf, c0, c1);

    for (int s = 1; s < T_STEPS; ++s) {
        const __half* h1p = hist + (size_t)(s - 1) * E;
        const __half* h0p = h0buf + (size_t)((s - 1) & 1) * E;
        __half* h0n = h0buf + (size_t)(s & 1) * E;
        __half* h1n = hist + (size_t)s * E;
        // layer 0: A=Qcomb x h1(s-1), B=Qhh0 x h0(s-1)
        k_stepq<<<E / 8, 512, 0, stream>>>(PA0, sA0, PB0, sB0, h1p, h0p, bcomb, c0, h0n);
        // layer 1: A=Qih1 x h0(s), B=Qhh1 x h1(s-1)
        k_stepq<<<E / 8, 512, 0, stream>>>(PA1, sA1, PB1, sB1, h0n, h1p, bias1, c1, h1n);
    }

    k_out<<<T_STEPS, 128, 0, stream>>>(woutT, hist, bout, (float*)d_out);
}

// Round 18
// 7622.095 us; speedup vs baseline: 1.0444x; 1.0444x over previous
//
#include <hip/hip_runtime.h>
#include <hip/hip_fp16.h>

typedef unsigned short u16;
typedef unsigned int u32;
typedef unsigned long long u64;

#define E 2048
#define T_STEPS 512

// ---------------- helpers ----------------
// dequant 8 int4 (offset-8 nibbles) from one u32 against 8 h-values
__device__ __forceinline__ float dot8i4(u32 v, float4 a, float4 b, float acc) {
    acc = fmaf((float)((int)(v & 15u) - 8), a.x, acc);
    acc = fmaf((float)((int)((v >> 4) & 15u) - 8), a.y, acc);
    acc = fmaf((float)((int)((v >> 8) & 15u) - 8), a.z, acc);
    acc = fmaf((float)((int)((v >> 12) & 15u) - 8), a.w, acc);
    acc = fmaf((float)((int)((v >> 16) & 15u) - 8), b.x, acc);
    acc = fmaf((float)((int)((v >> 20) & 15u) - 8), b.y, acc);
    acc = fmaf((float)((int)((v >> 24) & 15u) - 8), b.z, acc);
    acc = fmaf((float)((int)(v >> 28) - 8), b.w, acc);
    return acc;
}
// dequant 32 int3 (offset-4) packed in 96-bit (A,B,C) against 32 h-values
__device__ __forceinline__ float dot32i3(u32 A, u32 B, u32 C,
                                         const float4* __restrict__ h, float acc) {
    const u64 AB = ((u64)B << 32) | A;
    const u64 BC = ((u64)C << 32) | B;
    const float* hf = (const float*)h;
#pragma unroll
    for (int i = 0; i < 32; ++i) {
        u32 v;
        if (i <= 20) v = (u32)(AB >> (3 * i)) & 7u;          // compile-time shifts
        else         v = (u32)(BC >> (3 * i - 32)) & 7u;
        acc = fmaf((float)((int)v - 4), hf[i], acc);
    }
    return acc;
}
__device__ __forceinline__ float wred(float t) {
#pragma unroll
    for (int off = 32; off > 0; off >>= 1) t += __shfl_xor(t, off);
    return t;
}
__device__ __forceinline__ float sigm(float v) { return 1.f / (1.f + expf(-v)); }

// load 8 fp16 elems at h16 + idx (16B, wave-coalesced 1KB/instr) -> two float4
__device__ __forceinline__ void ld8h(const __half* __restrict__ h16, int idx,
                                     float4& f0, float4& f1) {
    uint4 u = *(const uint4*)(h16 + idx);
    float2 a = __half22float2(*reinterpret_cast<const __half2*>(&u.x));
    float2 b = __half22float2(*reinterpret_cast<const __half2*>(&u.y));
    float2 c = __half22float2(*reinterpret_cast<const __half2*>(&u.z));
    float2 d = __half22float2(*reinterpret_cast<const __half2*>(&u.w));
    f0 = make_float4(a.x, a.y, b.x, b.y);
    f1 = make_float4(c.x, c.y, d.x, d.y);
}

// ---------------- prep kernels ----------------

// W_comb[r][c] = sum_k W_ih0[r][k] * W_out[k][c]  (fp32; 8192 x 2048)
__global__ __launch_bounds__(256) void k_wcomb(const float* __restrict__ wih0,
                                               const float* __restrict__ wout,
                                               float* __restrict__ wc) {
    __shared__ float a[8 * 128];
    int r0 = blockIdx.y * 8;
    int c = blockIdx.x * 256 + threadIdx.x;
    for (int i = threadIdx.x; i < 8 * 128; i += 256) a[i] = wih0[r0 * 128 + i];
    __syncthreads();
    float acc[8] = {0.f, 0.f, 0.f, 0.f, 0.f, 0.f, 0.f, 0.f};
    for (int k = 0; k < 128; ++k) {
        float b = wout[k * E + c];
#pragma unroll
        for (int j = 0; j < 8; ++j) acc[j] = fmaf(a[j * 128 + k], b, acc[j]);
    }
#pragma unroll
    for (int j = 0; j < 8; ++j) wc[(size_t)(r0 + j) * E + c] = acc[j];
}

// int4 quantization: packed row p = e*4+q (256 u32).
// lane l covers elems {j*512 + l*8 .. +7}, j=0..3; uint4 component j = those 8 nibbles.
__global__ __launch_bounds__(64) void k_quant4p(const float* __restrict__ in,
                                                u32* __restrict__ P,
                                                float* __restrict__ sP) {
    const int r = blockIdx.x;
    const int l = threadIdx.x;
    const int q = r >> 11, e = r & 2047;
    const int p = e * 4 + q;
    const float* row = in + (size_t)r * E;
    float4 a[4], b[4];
    float mx = 0.f;
#pragma unroll
    for (int j = 0; j < 4; ++j) {
        a[j] = *(const float4*)(row + j * 512 + l * 8);
        b[j] = *(const float4*)(row + j * 512 + l * 8 + 4);
        mx = fmaxf(mx, fmaxf(fmaxf(fabsf(a[j].x), fabsf(a[j].y)),
                             fmaxf(fabsf(a[j].z), fabsf(a[j].w))));
        mx = fmaxf(mx, fmaxf(fmaxf(fabsf(b[j].x), fabsf(b[j].y)),
                             fmaxf(fabsf(b[j].z), fabsf(b[j].w))));
    }
#pragma unroll
    for (int off = 32; off > 0; off >>= 1) mx = fmaxf(mx, __shfl_xor(mx, off));
    mx = fmaxf(mx, 1e-30f);
    const float inv = 7.f / mx;
    u32 pk[4];
#pragma unroll
    for (int j = 0; j < 4; ++j) {
        const float* aj = (const float*)&a[j];
        const float* bj = (const float*)&b[j];
        u32 acc = 0u;
#pragma unroll
        for (int i = 0; i < 8; ++i) {
            float x = i < 4 ? aj[i] : bj[i - 4];
            int qv = (int)rintf(x * inv);
            qv = qv < -7 ? -7 : (qv > 7 ? 7 : qv);
            acc |= ((u32)(qv + 8)) << (4 * i);
        }
        pk[j] = acc;
    }
    ((uint4*)(P + (size_t)p * 256))[l] = make_uint4(pk[0], pk[1], pk[2], pk[3]);
    if (l == 0) sP[p] = mx / 7.f;
}

// int3 quantization: packed row p = e*4+q occupies 192 u32.
// lane l's 32 values (flat order j*8+i, elems j*512+l*8+i) -> 96-bit {A,B,C};
// A,B interleaved as uint2 at [p*192 + 2l], C at [p*192 + 128 + l].
__global__ __launch_bounds__(64) void k_quant3p(const float* __restrict__ in,
                                                u32* __restrict__ P,
                                                float* __restrict__ sP) {
    const int r = blockIdx.x;
    const int l = threadIdx.x;
    const int q = r >> 11, e = r & 2047;
    const int p = e * 4 + q;
    const float* row = in + (size_t)r * E;
    float fv[32];
    float mx = 0.f;
#pragma unroll
    for (int j = 0; j < 4; ++j) {
        float4 a = *(const float4*)(row + j * 512 + l * 8);
        float4 b = *(const float4*)(row + j * 512 + l * 8 + 4);
        fv[j * 8 + 0] = a.x; fv[j * 8 + 1] = a.y; fv[j * 8 + 2] = a.z; fv[j * 8 + 3] = a.w;
        fv[j * 8 + 4] = b.x; fv[j * 8 + 5] = b.y; fv[j * 8 + 6] = b.z; fv[j * 8 + 7] = b.w;
        mx = fmaxf(mx, fmaxf(fmaxf(fabsf(a.x), fabsf(a.y)), fmaxf(fabsf(a.z), fabsf(a.w))));
        mx = fmaxf(mx, fmaxf(fmaxf(fabsf(b.x), fabsf(b.y)), fmaxf(fabsf(b.z), fabsf(b.w))));
    }
#pragma unroll
    for (int off = 32; off > 0; off >>= 1) mx = fmaxf(mx, __shfl_xor(mx, off));
    mx = fmaxf(mx, 1e-30f);
    const float inv = 3.f / mx;
    u32 w3[3] = {0u, 0u, 0u};
#pragma unroll
    for (int i = 0; i < 32; ++i) {
        int qv = (int)rintf(fv[i] * inv);
        qv = qv < -3 ? -3 : (qv > 3 ? 3 : qv);
        const u32 u = (u32)(qv + 4);
        const int bit = 3 * i, word = bit >> 5, off = bit & 31;
        w3[word] |= u << off;
        if (off > 29 && word < 2) w3[word + 1] |= u >> (32 - off);
    }
    u32* dst = P + (size_t)p * 192;
    dst[2 * l] = w3[0];
    dst[2 * l + 1] = w3[1];
    dst[128 + l] = w3[2];
    if (l == 0) sP[p] = mx / 3.f;
}

// W_outT[e][d] = W_out[d][e]
__global__ void k_transpose_wout(const float* __restrict__ wout, float* __restrict__ woutT) {
    int o = blockIdx.x * blockDim.x + threadIdx.x;
    if (o >= E * 128) return;
    int e = o >> 7, d = o & 127;
    woutT[o] = wout[d * E + e];
}

// bcomb[r] = b_ih0[r]+b_hh0[r]+dot(W_ih0[r],b_out);  bias1[r] = b_ih1[r]+b_hh1[r]
__global__ void k_bcomb(const float* __restrict__ wih0, const float* __restrict__ bout,
                        const float* __restrict__ bih0, const float* __restrict__ bhh0,
                        const float* __restrict__ bih1, const float* __restrict__ bhh1,
                        float* __restrict__ bcomb, float* __restrict__ bias1) {
    int r = blockIdx.x * blockDim.x + threadIdx.x;
    if (r >= 4 * E) return;
    float acc = bih0[r] + bhh0[r];
    const float* w = wih0 + (size_t)r * 128;
#pragma unroll 8
    for (int k = 0; k < 128; ++k) acc = fmaf(w[k], bout[k], acc);
    bcomb[r] = acc;
    bias1[r] = bih1[r] + bhh1[r];
}

// hist[0] = lat (fp16), h0buf slot0 = lat (fp16), c0 = c1 = 0
__global__ void k_init(const float* __restrict__ lat, __half* __restrict__ hist0,
                       __half* __restrict__ h0buf0, float* __restrict__ c0,
                       float* __restrict__ c1) {
    int i = blockIdx.x * blockDim.x + threadIdx.x;
    if (i >= E) return;
    __half v = __float2half(lat[i]);
    hist0[i] = v;
    h0buf0[i] = v;
    c0[i] = 0.f;
    c1[i] = 0.f;
}

// ---------------- step kernel: one LSTM layer, 4 elems/block, 4 indep waves ----------
// wave w owns elem e = 4b + w. A-matrix int4 (PA + e*1024 u32) dots inA;
// B-matrix int3 (PB + e*768 u32) dots inB. No LDS, no syncs.
__global__ __launch_bounds__(256) void k_stepq(
    const u32* __restrict__ PA, const float* __restrict__ sA,
    const u32* __restrict__ PB, const float* __restrict__ sB,
    const __half* __restrict__ inA, const __half* __restrict__ inB,
    const float* __restrict__ bias, float* __restrict__ c,
    __half* __restrict__ hout) {
    const int e = blockIdx.x * 4 + (threadIdx.x >> 6);
    const int l = threadIdx.x & 63;

    // weight loads first (independent of predecessor kernel's output)
    const u32* wp4 = PA + (size_t)e * 1024;
    const u32* wp3 = PB + (size_t)e * 768;
    uint4 w4[4];
    uint2 ab3[4];
    u32 c3[4];
#pragma unroll
    for (int q = 0; q < 4; ++q) {
        w4[q] = ((const uint4*)(wp4 + q * 256))[l];
        ab3[q] = ((const uint2*)(wp3 + q * 192))[l];
        c3[q] = wp3[q * 192 + 128 + l];
    }

    // activations: 4 x 16B loads per vector (contiguous 8-elem groups per lane)
    float4 hA[8], hB[8];
#pragma unroll
    for (int j = 0; j < 4; ++j) {
        ld8h(inA, j * 512 + l * 8, hA[2 * j], hA[2 * j + 1]);
        ld8h(inB, j * 512 + l * 8, hB[2 * j], hB[2 * j + 1]);
    }

    const float* sAe = sA + e * 4;
    const float* sBe = sB + e * 4;
    float g[4];
#pragma unroll
    for (int q = 0; q < 4; ++q) {
        float accA = 0.f;
        accA = dot8i4(w4[q].x, hA[0], hA[1], accA);
        accA = dot8i4(w4[q].y, hA[2], hA[3], accA);
        accA = dot8i4(w4[q].z, hA[4], hA[5], accA);
        accA = dot8i4(w4[q].w, hA[6], hA[7], accA);
        float accB = dot32i3(ab3[q].x, ab3[q].y, c3[q], hB, 0.f);
        g[q] = wred(accA * sAe[q] + accB * sBe[q]);
    }

    if (l == 0) {
        float gi = g[0] + bias[e];
        float gf = g[1] + bias[E + e];
        float gg = g[2] + bias[2 * E + e];
        float go = g[3] + bias[3 * E + e];
        float cn = fmaf(sigm(gf), c[e], sigm(gi) * tanhf(gg));
        c[e] = cn;
        hout[e] = __float2half(sigm(go) * tanhf(cn));
    }
}

// ---------------- final output GEMM: out[t] = Wout @ hist[t] + bout ----------------
__global__ __launch_bounds__(128) void k_out(const float* __restrict__ woutT,
                                             const __half* __restrict__ hist,
                                             const float* __restrict__ bout,
                                             float* __restrict__ out) {
    __shared__ float h[E];
    int t = blockIdx.x, d = threadIdx.x;
    for (int i = d; i < E; i += 128) h[i] = __half2float(hist[(size_t)t * E + i]);
    __syncthreads();
    float acc0 = bout[d], acc1 = 0.f;
#pragma unroll 4
    for (int k = 0; k < E; k += 2) {
        acc0 = fmaf(woutT[k * 128 + d], h[k], acc0);
        acc1 = fmaf(woutT[(k + 1) * 128 + d], h[k + 1], acc1);
    }
    out[t * 128 + d] = acc0 + acc1;
}

extern "C" void kernel_launch(void* const* d_in, const int* in_sizes, int n_in,
                              void* d_out, int out_size, void* d_ws, size_t ws_size,
                              hipStream_t stream) {
    const float* lat = (const float*)d_in[0];
    const float* wih0 = (const float*)d_in[1];
    const float* whh0 = (const float*)d_in[2];
    const float* bih0 = (const float*)d_in[3];
    const float* bhh0 = (const float*)d_in[4];
    const float* wih1 = (const float*)d_in[5];
    const float* whh1 = (const float*)d_in[6];
    const float* bih1 = (const float*)d_in[7];
    const float* bhh1 = (const float*)d_in[8];
    const float* wout = (const float*)d_in[9];
    const float* bout = (const float*)d_in[10];

    const size_t P4B = (size_t)E * 4096;  // int4: 8.39 MB
    const size_t P3B = (size_t)E * 3072;  // int3: 6.29 MB
    char* p = (char*)d_ws;
    u32* PA0 = (u32*)p; p += P4B;  // layer0 cross: Qcomb (x h1)
    u32* PB0 = (u32*)p; p += P3B;  // layer0 recur: Qhh0 (x h0)
    u32* PA1 = (u32*)p; p += P4B;  // layer1 cross: Qih1 (x h0)
    u32* PB1 = (u32*)p; p += P3B;  // layer1 recur: Qhh1 (x h1)
    float* sA0 = (float*)p; p += (size_t)4 * E * 4;
    float* sB0 = (float*)p; p += (size_t)4 * E * 4;
    float* sA1 = (float*)p; p += (size_t)4 * E * 4;
    float* sB1 = (float*)p; p += (size_t)4 * E * 4;
    float* WcF = (float*)p; p += (size_t)4 * E * E * 4;  // 67 MB temp
    float* woutT = (float*)p; p += (size_t)E * 128 * 4;
    float* bcomb = (float*)p; p += (size_t)4 * E * 4;
    float* bias1 = (float*)p; p += (size_t)4 * E * 4;
    __half* hist = (__half*)p;  p += (size_t)T_STEPS * E * 2;
    __half* h0buf = (__half*)p; p += (size_t)2 * E * 2;
    float* c0 = (float*)p;    p += (size_t)E * 4;
    float* c1 = (float*)p;    p += (size_t)E * 4;

    k_wcomb<<<dim3(8, 1024), 256, 0, stream>>>(wih0, wout, WcF);
    k_quant4p<<<4 * E, 64, 0, stream>>>(WcF, PA0, sA0);
    k_quant3p<<<4 * E, 64, 0, stream>>>(whh0, PB0, sB0);
    k_quant4p<<<4 * E, 64, 0, stream>>>(wih1, PA1, sA1);
    k_quant3p<<<4 * E, 64, 0, stream>>>(whh1, PB1, sB1);
    k_transpose_wout<<<(E * 128 + 255) / 256, 256, 0, stream>>>(wout, woutT);
    k_bcomb<<<(4 * E + 255) / 256, 256, 0, stream>>>(wih0, bout, bih0, bhh0, bih1, bhh1,
                                                     bcomb, bias1);
    k_init<<<(E + 255) / 256, 256, 0, stream>>>(lat, hist, h0buf, c0, c1);

    for (int s = 1; s < T_STEPS; ++s) {
        const __half* h1p = hist + (size_t)(s - 1) * E;
        const __half* h0p = h0buf + (size_t)((s - 1) & 1) * E;
        __half* h0n = h0buf + (size_t)(s & 1) * E;
        __half* h1n = hist + (size_t)s * E;
        // layer 0: A=Qcomb x h1(s-1), B=Qhh0 x h0(s-1)
        k_stepq<<<E / 4, 256, 0, stream>>>(PA0, sA0, PB0, sB0, h1p, h0p, bcomb, c0, h0n);
        // layer 1: A=Qih1 x h0(s), B=Qhh1 x h1(s-1)
        k_stepq<<<E / 4, 256, 0, stream>>>(PA1, sA1, PB1, sB1, h0n, h1p, bias1, c1, h1n);
    }

    k_out<<<T_STEPS, 128, 0, stream>>>(woutT, hist, bout, (float*)d_out);
}